// Round 1
// baseline (110.469 us; speedup 1.0000x reference)
//
#include <hip/hip_runtime.h>

#define NP 8192
#define CAP 32

// Phase 1: one block per true row. Compute distances to all pred points,
// collect candidates (true_occ & pred_occ & d<=1), sort by (d, j) asc.
__global__ void build_cands(const float4* __restrict__ pred,
                            const float4* __restrict__ truec,
                            int* __restrict__ cnt,
                            int* __restrict__ cj,
                            float* __restrict__ cd) {
    int i = blockIdx.x;
    __shared__ int c;
    __shared__ int   sj[CAP];
    __shared__ float sd[CAP];
    if (threadIdx.x == 0) c = 0;
    __syncthreads();
    float4 t = truec[i];
    if (t.w >= 0.5f) {
        for (int j = threadIdx.x; j < NP; j += 256) {
            float4 p = pred[j];
            if (p.w >= 0.5f) {
                float dx = t.x - p.x, dy = t.y - p.y, dz = t.z - p.z;
                float d = sqrtf(dx*dx + dy*dy + dz*dz);
                if (d <= 1.0f) {
                    int k = atomicAdd(&c, 1);
                    if (k < CAP) { sj[k] = j; sd[k] = d; }
                }
            }
        }
    }
    __syncthreads();
    int cc = c < CAP ? c : CAP;
    if (threadIdx.x == 0) {
        // insertion sort by (d, j) ascending -> reproduces argmin tie-break
        for (int a = 1; a < cc; ++a) {
            float dv = sd[a]; int jv = sj[a]; int b = a - 1;
            while (b >= 0 && (sd[b] > dv || (sd[b] == dv && sj[b] > jv))) {
                sd[b+1] = sd[b]; sj[b+1] = sj[b]; --b;
            }
            sd[b+1] = dv; sj[b+1] = jv;
        }
        cnt[i] = cc;
    }
    __syncthreads();
    for (int k = threadIdx.x; k < cc; k += 256) {
        cj[(size_t)i*CAP + k] = sj[k];
        cd[(size_t)i*CAP + k] = sd[k];
    }
}

// Phase 2: single block. Parallel (Jacobi) deferred acceptance with common
// column priority = row index. Fixed point == serial greedy matching of the
// reference scan. Then reduce to the scalar loss.
__global__ __launch_bounds__(1024)
void match_reduce(const float4* __restrict__ pred,
                  const float4* __restrict__ truec,
                  const int* __restrict__ cnt,
                  const int* __restrict__ cj,
                  const float* __restrict__ cd,
                  float* __restrict__ out) {
    __shared__ int H[NP];              // column -> lowest chooser row (32KB)
    __shared__ unsigned short C[NP];   // row -> chosen position in its list (16KB)
    __shared__ unsigned char CN[NP];   // row -> candidate count (8KB)
    __shared__ int changed;
    __shared__ float redf[2][16];
    __shared__ int   redi[2][16];
    int tid = threadIdx.x;

    for (int r = tid; r < NP; r += 1024) {
        H[r] = 0x7FFFFFFF;
        C[r] = 0xFFFF;
        CN[r] = (unsigned char)cnt[r];
    }
    __syncthreads();

    for (int it = 0; it < NP; ++it) {
        if (tid == 0) changed = 0;
        __syncthreads();
        // scan: each active row picks first candidate not held by a better row
        for (int r = tid; r < NP; r += 1024) {
            int n = CN[r];
            if (!n) continue;
            const int* rowj = cj + (size_t)r * CAP;
            int pick = -1;
            for (int p = 0; p < n; ++p) {
                if (H[rowj[p]] >= r) { pick = p; break; }
            }
            unsigned short pc = (pick < 0) ? (unsigned short)0xFFFF
                                           : (unsigned short)pick;
            if (pc != C[r]) { C[r] = pc; changed = 1; }
        }
        __syncthreads();
        if (!changed) break;   // fixed point: C is the greedy matching
        // rebuild H from choices
        for (int r = tid; r < NP; r += 1024) H[r] = 0x7FFFFFFF;
        __syncthreads();
        for (int r = tid; r < NP; r += 1024) {
            unsigned short p = C[r];
            if (p != 0xFFFF) atomicMin(&H[cj[(size_t)r*CAP + p]], r);
        }
        __syncthreads();
    }

    // final reduction
    float sdist = 0.f, sprob = 0.f;
    int nm = 0, nocc = 0;
    for (int r = tid; r < NP; r += 1024) {
        float tp = truec[r].w;
        if (tp >= 0.5f) ++nocc;
        unsigned short p = C[r];
        if (p != 0xFFFF) {
            int j = cj[(size_t)r*CAP + p];
            ++nm;
            sdist += cd[(size_t)r*CAP + p];
            float dp = tp - pred[j].w;
            sprob += dp * dp;
        }
    }
    for (int off = 32; off; off >>= 1) {
        sdist += __shfl_down(sdist, off);
        sprob += __shfl_down(sprob, off);
        nm    += __shfl_down(nm, off);
        nocc  += __shfl_down(nocc, off);
    }
    int wave = tid >> 6, lane = tid & 63;
    if (lane == 0) {
        redf[0][wave] = sdist; redf[1][wave] = sprob;
        redi[0][wave] = nm;    redi[1][wave] = nocc;
    }
    __syncthreads();
    if (tid == 0) {
        float S = 0.f, P = 0.f; int NM = 0, NO = 0;
        for (int w = 0; w < 16; ++w) {
            S += redf[0][w]; P += redf[1][w];
            NM += redi[0][w]; NO += redi[1][w];
        }
        float nmf = (float)NM;
        float unm = (float)NO - nmf;
        float mean_dist = S / nmf;
        float prob_mse  = P / nmf;
        out[0] = (mean_dist + 10.0f * unm) + (prob_mse + unm);
    }
}

extern "C" void kernel_launch(void* const* d_in, const int* in_sizes, int n_in,
                              void* d_out, int out_size, void* d_ws, size_t ws_size,
                              hipStream_t stream) {
    const float4* pred  = (const float4*)d_in[0];
    const float4* truec = (const float4*)d_in[1];
    float* out = (float*)d_out;

    int*   cnt = (int*)d_ws;                       // NP ints
    int*   cj  = cnt + NP;                         // NP*CAP ints
    float* cd  = (float*)(cj + (size_t)NP * CAP);  // NP*CAP floats

    build_cands<<<NP, 256, 0, stream>>>(pred, truec, cnt, cj, cd);
    match_reduce<<<1, 1024, 0, stream>>>(pred, truec, cnt, cj, cd, out);
}